// Round 5
// baseline (258226.465 us; speedup 1.0000x reference)
//
#include <hip/hip_runtime.h>

#define T_STEPS 100000
#define NLAUNCH 1024   // candidate workgroups (participants selected at runtime)
#define NPART 32       // participants, ideally co-located on ONE XCD
#define TPB 512        // 8 waves
#define HD 512
#define ID 128
#define UPW 16         // hidden units per participant (HD/NPART)
#define ROWS 64        // gate rows per participant = 4*UPW
#define GUARD_MAIN (1u << 23)
#define HS_SPIN    (1u << 16)   // ~8 ms worst-case if placement is broken
#define OK_SPIN    (1u << 22)

// d_ws layout (ull units):
// [0,1024): hpk[2][512] packed {tag,val}
// [1024]   : ctrl (u32[2]: chosen+1, claims)
// [1025,1057): hs[32]  L2-scope handshake magics
// [1057,1089): okw[32] device-scope handshake outcomes
#define CTRL_OFF 1024
#define HS_OFF   1025
#define OK_OFF   1057
#define WS_CLEAR ((OK_OFF + 32) * 8)

// ---- L2-executed atomic RMWs (no sc1 -> stay in the XCD's L2; tear-free) ----
__device__ inline unsigned long long l2_read(unsigned long long* p) {
  unsigned long long old; unsigned long long zero = 0;
  asm volatile("global_atomic_or_x2 %0, %1, %2, off sc0\n\ts_waitcnt vmcnt(0)"
               : "=&v"(old) : "v"(p), "v"(zero) : "memory");
  return old;
}
__device__ inline void l2_write(unsigned long long* p, unsigned long long v) {
  asm volatile("global_atomic_swap_x2 %0, %1, off" :: "v"(p), "v"(v) : "memory");
}
// ---- proven agent-scope path (round 1, absmax 0.0) ----
__device__ inline unsigned long long dev_read(unsigned long long* p) {
  return __hip_atomic_load(p, __ATOMIC_RELAXED, __HIP_MEMORY_SCOPE_AGENT);
}
__device__ inline void dev_write(unsigned long long* p, unsigned long long v) {
  __hip_atomic_store(p, v, __ATOMIC_RELAXED, __HIP_MEMORY_SCOPE_AGENT);
}

__device__ inline unsigned long long poll_tag(unsigned long long* p, unsigned int tag,
                                              bool fast, bool& dead) {
  unsigned long long v;
  if (!dead) {
    unsigned int g = 0;
    do { v = fast ? l2_read(p) : dev_read(p); }
    while ((unsigned int)(v >> 32) != tag && ++g < GUARD_MAIN);
    if (g >= GUARD_MAIN) dead = true;
  } else {
    v = fast ? l2_read(p) : dev_read(p);
  }
  return v;
}

__global__ __launch_bounds__(TPB, 2) void lstm_persist(
    const float* __restrict__ x,      // [T,128]
    const float* __restrict__ W_ih,   // [2048,128]
    const float* __restrict__ b_ih,   // [2048]
    const float* __restrict__ W_hh,   // [2048,512]
    const float* __restrict__ b_hh,   // [2048]
    const float* __restrict__ W_out,  // [512]
    const float* __restrict__ b_out,  // [1]
    float* __restrict__ out,          // [T]
    unsigned long long* __restrict__ ws)
{
  unsigned long long* hpk = ws;                        // [2][512]
  unsigned int* ctrl = (unsigned int*)(ws + CTRL_OFF); // [0]=chosen+1 [1]=claims

  const int tid  = threadIdx.x;  // 0..511
  const int wave = tid >> 6;     // 0..7
  const int lane = tid & 63;
  const int qr   = tid >> 3;     // reduction row 0..63
  const int c8   = tid & 7;      // reduction chunk 0..7

  __shared__ int role_sh;
  __shared__ unsigned int cnt_sh;
  __shared__ float h_lds[HD];
  __shared__ float part_lds[ROWS][65];
  __shared__ float gates_lds[ROWS];
  __shared__ float xp_lds[2][ROWS];
  __shared__ float bsum_lds[ROWS];

  // ---- participant selection: first 32 wgs on the elected XCD ----
  unsigned int xcc;
  asm volatile("s_getreg_b32 %0, hwreg(HW_REG_XCC_ID)" : "=s"(xcc));
  if (tid == 0) {
    int role = -1;
    unsigned int prev = atomicCAS(&ctrl[0], 0u, xcc + 1u);
    unsigned int chosen = (prev == 0u) ? xcc : (prev - 1u);
    if (xcc == chosen) {
      unsigned int idx = atomicAdd(&ctrl[1], 1u);
      if (idx < NPART) role = (int)idx;
    }
    role_sh = role;
  }
  __syncthreads();
  const int w = role_sh;         // participant id 0..31, or -1
  if (w < 0) return;

  // ---- handshake: verify L2-scope visibility among all 32 participants ----
  bool fast;
  {
    if (tid == 0) {
      cnt_sh = 0;
      l2_write(&ws[HS_OFF + w],
               0xC0DEC0DE00000000ull | (unsigned long long)(w + 1));
    }
    __syncthreads();
    if (tid < NPART) {
      const unsigned long long want =
          0xC0DEC0DE00000000ull | (unsigned long long)(tid + 1);
      unsigned int g = 0;
      while (l2_read(&ws[HS_OFF + tid]) != want && ++g < HS_SPIN) {}
      if (g < HS_SPIN) atomicAdd(&cnt_sh, 1u);
    }
    __syncthreads();
    const bool all_ok = (cnt_sh == NPART);
    __syncthreads();                       // everyone read cnt before reset
    if (tid == 0) {
      cnt_sh = 0;
      dev_write(&ws[OK_OFF + w], all_ok ? 1ull : 2ull);  // proven channel
    }
    __syncthreads();
    if (tid < NPART) {
      unsigned long long v; unsigned int g = 0;
      do { v = dev_read(&ws[OK_OFF + tid]); } while (v == 0ull && ++g < OK_SPIN);
      if (v == 1ull) atomicAdd(&cnt_sh, 1u);
    }
    __syncthreads();
    fast = (cnt_sh == NPART);   // uniform across all participants
  }

  // local gate-row q (0..63) -> global row: gate=(q>>4), unit=16*w+(q&15)
  // ---- stage weights into registers (one-time) ----
  float Whh[8][8];  // wave owns rows q=wave*8+p; lane covers k = lane+64*j
  #pragma unroll
  for (int p = 0; p < 8; ++p) {
    const int q = wave*8 + p;
    const int R = (q>>4)*HD + UPW*w + (q&15);
    const float* src = W_hh + (size_t)R*HD + lane;
    #pragma unroll
    for (int j = 0; j < 8; ++j) Whh[p][j] = src[64*j];
  }
  float Wih[16];    // thread (qr,c8) owns row qr, k in [c8*16, c8*16+16)
  {
    const int R = (qr>>4)*HD + UPW*w + (qr&15);
    const float* src = W_ih + (size_t)R*ID + c8*16;
    #pragma unroll
    for (int i = 0; i < 16; ++i) Wih[i] = src[i];
  }
  float Wo[8];
  if (wave == 0) {
    #pragma unroll
    for (int j = 0; j < 8; ++j) Wo[j] = W_out[lane + 64*j];
  }
  const float bo = b_out[0];

  if (tid < ROWS) {
    const int R = (tid>>4)*HD + UPW*w + (tid&15);
    bsum_lds[tid] = b_ih[R] + b_hh[R];
  }
  __syncthreads();

  // h0 (tag 0, value 0.0) is provided by the hipMemsetAsync zero-fill.

  // input projection for x row 0 (consumed at iter t=1)
  {
    float s = 0.f;
    const float* xr = x + c8*16;
    #pragma unroll
    for (int i = 0; i < 16; ++i) s += Wih[i]*xr[i];
    s += __shfl_xor(s, 1); s += __shfl_xor(s, 2); s += __shfl_xor(s, 4);
    if (c8 == 0) xp_lds[0][qr] = s + bsum_lds[qr];
  }

  float creg = 0.f;    // cell state for unit (16*w + tid), tid<16
  bool dead = false;   // sticky guard-trip flag: degrade fast, never hang

  for (int t = 1; t <= T_STEPS; ++t) {
    const unsigned int tag = (unsigned int)(t - 1);
    unsigned long long* sl = hpk + (size_t)((t - 1) & 1) * HD;

    // ---- poll + gather h_{t-1}: one element per thread ----
    const unsigned long long v = poll_tag(&sl[tid], tag, fast, dead);
    h_lds[tid] = __uint_as_float((unsigned int)v);
    __syncthreads();   // sync1: h ready

    // ---- output p_{t-1} -> out[t-2], round-robin across participants ----
    if (wave == 0 && t >= 2 && ((t - 2) & (NPART - 1)) == w) {
      float s = 0.f;
      #pragma unroll
      for (int j = 0; j < 8; ++j) s = fmaf(Wo[j], h_lds[lane + 64*j], s);
      s += __shfl_xor(s, 1);  s += __shfl_xor(s, 2);  s += __shfl_xor(s, 4);
      s += __shfl_xor(s, 8);  s += __shfl_xor(s, 16); s += __shfl_xor(s, 32);
      if (lane == 0) out[t - 2] = 1.f / (1.f + __expf(-(s + bo)));
    }

    // ---- matvec partials: 64 FMAs/lane from registers ----
    float hreg[8];
    #pragma unroll
    for (int j = 0; j < 8; ++j) hreg[j] = h_lds[lane + 64*j];
    #pragma unroll
    for (int p = 0; p < 8; ++p) {
      float s = 0.f;
      #pragma unroll
      for (int j = 0; j < 8; ++j) s = fmaf(Whh[p][j], hreg[j], s);
      part_lds[wave*8 + p][lane] = s;
    }
    __syncthreads();   // sync2: partials ready

    // ---- reduce 64 lane-partials per row -> gates ----
    {
      float s = 0.f;
      #pragma unroll
      for (int i = 0; i < 8; ++i) s += part_lds[qr][c8*8 + i];
      s += __shfl_xor(s, 1); s += __shfl_xor(s, 2); s += __shfl_xor(s, 4);
      if (c8 == 0) gates_lds[qr] = s + xp_lds[(t - 1) & 1][qr];
    }
    __syncthreads();   // sync3: gates ready

    // ---- activations, cell update, publish h_t (16 threads) ----
    if (tid < UPW) {
      const float ii = 1.f / (1.f + __expf(-gates_lds[tid]));
      const float ff = 1.f / (1.f + __expf(-gates_lds[16 + tid]));
      const float e2g = __expf(2.f * gates_lds[32 + tid]);
      const float gg = 1.f - 2.f / (e2g + 1.f);
      const float oo = 1.f / (1.f + __expf(-gates_lds[48 + tid]));
      creg = ff * creg + ii * gg;
      const float e2c = __expf(2.f * creg);
      const float hh = oo * (1.f - 2.f / (e2c + 1.f));
      const unsigned long long pk =
          ((unsigned long long)(unsigned int)t << 32) |
          (unsigned long long)__float_as_uint(hh);
      unsigned long long* dst = &hpk[(size_t)(t & 1) * HD + UPW*w + tid];
      if (fast) l2_write(dst, pk); else dev_write(dst, pk);
    }

    // ---- input projection for x row t (consumed next iter) ----
    if (t < T_STEPS) {
      float s = 0.f;
      const float* xr = x + (size_t)t * ID + c8*16;
      #pragma unroll
      for (int i = 0; i < 16; ++i) s += Wih[i]*xr[i];
      s += __shfl_xor(s, 1); s += __shfl_xor(s, 2); s += __shfl_xor(s, 4);
      if (c8 == 0) xp_lds[t & 1][qr] = s + bsum_lds[qr];
    }
  }

  // ---- tail: out[T-1] = sigmoid(W_out . h_T + b), by participant 0 ----
  if (w == 0) {
    unsigned long long* sl = hpk + (size_t)(T_STEPS & 1) * HD;
    const unsigned long long v =
        poll_tag(&sl[tid], (unsigned int)T_STEPS, fast, dead);
    h_lds[tid] = __uint_as_float((unsigned int)v);
    __syncthreads();
    if (wave == 0) {
      float s = 0.f;
      #pragma unroll
      for (int j = 0; j < 8; ++j) s = fmaf(Wo[j], h_lds[lane + 64*j], s);
      s += __shfl_xor(s, 1);  s += __shfl_xor(s, 2);  s += __shfl_xor(s, 4);
      s += __shfl_xor(s, 8);  s += __shfl_xor(s, 16); s += __shfl_xor(s, 32);
      if (lane == 0) out[T_STEPS - 1] = 1.f / (1.f + __expf(-(s + bo)));
    }
  }
}

extern "C" void kernel_launch(void* const* d_in, const int* in_sizes, int n_in,
                              void* d_out, int out_size, void* d_ws, size_t ws_size,
                              hipStream_t stream) {
  (void)in_sizes; (void)n_in; (void)out_size; (void)ws_size;
  const float* x     = (const float*)d_in[0];
  const float* W_ih  = (const float*)d_in[1];
  const float* b_ih  = (const float*)d_in[2];
  const float* W_hh  = (const float*)d_in[3];
  const float* b_hh  = (const float*)d_in[4];
  const float* W_out = (const float*)d_in[5];
  const float* b_out = (const float*)d_in[6];
  float* out = (float*)d_out;
  unsigned long long* ws = (unsigned long long*)d_ws;

  // Zero mailbox + ctrl + handshake words: provides h0={tag0,0.f} and resets
  // election/handshake state. Stream op -> graph-capture safe.
  hipMemsetAsync(d_ws, 0, WS_CLEAR, stream);

  lstm_persist<<<NLAUNCH, TPB, 0, stream>>>(x, W_ih, b_ih, W_hh, b_hh,
                                            W_out, b_out, out, ws);
}

// Round 11
// 184319.092 us; speedup vs baseline: 1.4010x; 1.4010x over previous
//
#include <hip/hip_runtime.h>

#define T_STEPS 100000
#define NWG 32
#define TPB 512        // 8 waves
#define HD 512
#define ID 128
#define UPW 16         // hidden units per workgroup
#define ROWS 64        // gate rows per workgroup = 4*UPW
#define GUARD (1u << 27)

// Communication: agent-scope relaxed 8B atomics, packed {tag32, val32}.
// PROVEN absmax 0.0 (round 1). sc0 plain-access fast paths all failed
// (rounds 4/6/8) — do not revisit without new hardware evidence.
__device__ inline unsigned long long dev_read(unsigned long long* p) {
  return __hip_atomic_load(p, __ATOMIC_RELAXED, __HIP_MEMORY_SCOPE_AGENT);
}
__device__ inline void dev_write(unsigned long long* p, unsigned long long v) {
  __hip_atomic_store(p, v, __ATOMIC_RELAXED, __HIP_MEMORY_SCOPE_AGENT);
}

__global__ __launch_bounds__(TPB, 2) void lstm_persist(
    const float* __restrict__ x,      // [T,128]
    const float* __restrict__ W_ih,   // [2048,128]
    const float* __restrict__ b_ih,   // [2048]
    const float* __restrict__ W_hh,   // [2048,512]
    const float* __restrict__ b_hh,   // [2048]
    const float* __restrict__ W_out,  // [512]
    const float* __restrict__ b_out,  // [1]
    float* __restrict__ out,          // [T]
    unsigned long long* __restrict__ mbx) // [2][512] packed {tag,val}
{
  const int w    = blockIdx.x;   // participant 0..31
  const int tid  = threadIdx.x;  // 0..511
  const int v    = tid >> 6;     // wave 0..7
  const int l    = tid & 63;     // lane
  const int q    = v * 8 + (l >> 3);  // this thread's gate row 0..63
  const int k8   = l & 7;             // h-chunk [64*k8, 64*k8+64)
  const int qr   = tid >> 3;     // xp row 0..63
  const int c8   = tid & 7;      // xp chunk 0..7

  // h double-buffer: [parity][chunk][68] — 68 keeps float4 alignment and
  // spreads the 8 chunk-groups across distinct bank quads (conflict-free).
  __shared__ float h_lds[2][8][68];
  __shared__ float gates_lds[ROWS];
  __shared__ float xp_lds[2][ROWS];
  __shared__ float bsum_lds[ROWS];

  // global gate row for compute mapping: gate=(q>>4), unit=16*w+(q&15)
  const int G = (q >> 4) * HD + UPW * w + (q & 15);

  // ---- stage weights into registers (one-time) ----
  float Whh[64];   // row G, h-elements [64*k8, 64*k8+64)
  {
    const float* src = W_hh + (size_t)G * HD + 64 * k8;
    #pragma unroll
    for (int jj = 0; jj < 16; ++jj) {
      const float4 t4 = *reinterpret_cast<const float4*>(src + 4 * jj);
      Whh[4*jj]   = t4.x; Whh[4*jj+1] = t4.y;
      Whh[4*jj+2] = t4.z; Whh[4*jj+3] = t4.w;
    }
  }
  float Wih[16];   // xp mapping: row qr, k in [c8*16, c8*16+16)
  {
    const int R = (qr >> 4) * HD + UPW * w + (qr & 15);
    const float* src = W_ih + (size_t)R * ID + c8 * 16;
    #pragma unroll
    for (int i = 0; i < 16; ++i) Wih[i] = src[i];
  }
  float Wo[8];     // wave 1 owns the readout projection
  if (v == 1) {
    #pragma unroll
    for (int j = 0; j < 8; ++j) Wo[j] = W_out[l + 64 * j];
  }
  const float bo = b_out[0];

  if (tid < ROWS) {
    const int R = (tid >> 4) * HD + UPW * w + (tid & 15);
    bsum_lds[tid] = b_ih[R] + b_hh[R];
  }
  __syncthreads();

  // h0 (tag 0, value 0.0) provided by the hipMemsetAsync zero-fill.

  // input projection for x row 0 (consumed at iter t=1)
  {
    float s = 0.f;
    const float* xr = x + c8 * 16;
    #pragma unroll
    for (int i = 0; i < 16; ++i) s += Wih[i] * xr[i];
    s += __shfl_xor(s, 1); s += __shfl_xor(s, 2); s += __shfl_xor(s, 4);
    if (c8 == 0) xp_lds[0][qr] = s + bsum_lds[qr];
  }

  float creg = 0.f;    // cell state for unit (16*w + tid), tid<16
  bool dead = false;   // sticky guard-trip: degrade fast, never hang

  for (int t = 1; t <= T_STEPS; ++t) {
    const unsigned int tag = (unsigned int)(t - 1);
    const int p = (t - 1) & 1;           // slot parity AND h_lds buffer
    unsigned long long* sl = mbx + (size_t)p * HD;

    // ---- A: poll + gather h_{t-1}: one element per thread ----
    unsigned long long pv;
    if (!dead) {
      unsigned int g = 0;
      do { pv = dev_read(&sl[tid]); }
      while ((unsigned int)(pv >> 32) != tag && ++g < GUARD);
      if (g >= GUARD) dead = true;
    } else {
      pv = dev_read(&sl[tid]);
    }
    h_lds[p][tid >> 6][tid & 63] = __uint_as_float((unsigned int)pv);
    __syncthreads();   // sync1: h ready (also fences xp/gates reuse)

    // ---- C: matvec row q over chunk k8: 64 reg-FMAs, in-wave reduce ----
    {
      float s = 0.f;
      const float* hrow = &h_lds[p][k8][0];
      #pragma unroll
      for (int jj = 0; jj < 16; ++jj) {
        const float4 h4 = *reinterpret_cast<const float4*>(hrow + 4 * jj);
        s = fmaf(Whh[4*jj],   h4.x, s);
        s = fmaf(Whh[4*jj+1], h4.y, s);
        s = fmaf(Whh[4*jj+2], h4.z, s);
        s = fmaf(Whh[4*jj+3], h4.w, s);
      }
      s += __shfl_xor(s, 1); s += __shfl_xor(s, 2); s += __shfl_xor(s, 4);
      if ((l & 7) == 0) gates_lds[q] = s + xp_lds[p][q];
    }
    __syncthreads();   // sync2: gates ready

    // ---- E: activations + publish (tid<16) FIRST — critical path ----
    if (tid < UPW) {
      const float ii = 1.f / (1.f + __expf(-gates_lds[tid]));
      const float ff = 1.f / (1.f + __expf(-gates_lds[16 + tid]));
      const float e2g = __expf(2.f * gates_lds[32 + tid]);
      const float gg = 1.f - 2.f / (e2g + 1.f);
      const float oo = 1.f / (1.f + __expf(-gates_lds[48 + tid]));
      creg = ff * creg + ii * gg;
      const float e2c = __expf(2.f * creg);
      const float hh = oo * (1.f - 2.f / (e2c + 1.f));
      const unsigned long long pk =
          ((unsigned long long)(unsigned int)t << 32) |
          (unsigned long long)__float_as_uint(hh);
      dev_write(&mbx[(size_t)(t & 1) * HD + UPW * w + tid], pk);
    }

    // ---- shadow work: out[t-2] (wave 1, round-robin over participants) ----
    if (v == 1 && t >= 2 && ((t - 2) & (NWG - 1)) == w) {
      float s = 0.f;
      #pragma unroll
      for (int j = 0; j < 8; ++j) s = fmaf(Wo[j], h_lds[p][j][l], s);
      s += __shfl_xor(s, 1);  s += __shfl_xor(s, 2);  s += __shfl_xor(s, 4);
      s += __shfl_xor(s, 8);  s += __shfl_xor(s, 16); s += __shfl_xor(s, 32);
      if (l == 0) out[t - 2] = 1.f / (1.f + __expf(-(s + bo)));
    }

    // ---- shadow work: input projection for x row t ----
    if (t < T_STEPS) {
      float s = 0.f;
      const float* xr = x + (size_t)t * ID + c8 * 16;
      #pragma unroll
      for (int i = 0; i < 16; ++i) s += Wih[i] * xr[i];
      s += __shfl_xor(s, 1); s += __shfl_xor(s, 2); s += __shfl_xor(s, 4);
      if (c8 == 0) xp_lds[t & 1][qr] = s + bsum_lds[qr];
    }
    // no trailing barrier: next gather writes h_lds[p^1]; gates_lds /
    // xp_lds reuse is ordered by the next iteration's sync1.
  }

  // ---- tail: out[T-1] = sigmoid(W_out . h_T + b), by participant 0 ----
  if (w == 0) {
    const int p = T_STEPS & 1;
    unsigned long long* sl = mbx + (size_t)p * HD;
    unsigned long long pv;
    if (!dead) {
      unsigned int g = 0;
      do { pv = dev_read(&sl[tid]); }
      while ((unsigned int)(pv >> 32) != (unsigned int)T_STEPS && ++g < GUARD);
    } else {
      pv = dev_read(&sl[tid]);
    }
    h_lds[p][tid >> 6][tid & 63] = __uint_as_float((unsigned int)pv);
    __syncthreads();
    if (v == 1) {
      float s = 0.f;
      #pragma unroll
      for (int j = 0; j < 8; ++j) s = fmaf(Wo[j], h_lds[p][j][l], s);
      s += __shfl_xor(s, 1);  s += __shfl_xor(s, 2);  s += __shfl_xor(s, 4);
      s += __shfl_xor(s, 8);  s += __shfl_xor(s, 16); s += __shfl_xor(s, 32);
      if (l == 0) out[T_STEPS - 1] = 1.f / (1.f + __expf(-(s + bo)));
    }
  }
}

extern "C" void kernel_launch(void* const* d_in, const int* in_sizes, int n_in,
                              void* d_out, int out_size, void* d_ws, size_t ws_size,
                              hipStream_t stream) {
  (void)in_sizes; (void)n_in; (void)out_size; (void)ws_size;
  const float* x     = (const float*)d_in[0];
  const float* W_ih  = (const float*)d_in[1];
  const float* b_ih  = (const float*)d_in[2];
  const float* W_hh  = (const float*)d_in[3];
  const float* b_hh  = (const float*)d_in[4];
  const float* W_out = (const float*)d_in[5];
  const float* b_out = (const float*)d_in[6];
  float* out = (float*)d_out;
  unsigned long long* mbx = (unsigned long long*)d_ws;  // 2*512*8 = 8 KB

  // Zero mailbox: provides h0 = {tag 0, value 0.0}. Graph-capture safe.
  hipMemsetAsync(d_ws, 0, 2 * HD * sizeof(unsigned long long), stream);

  lstm_persist<<<NWG, TPB, 0, stream>>>(x, W_ih, b_ih, W_hh, b_hh,
                                        W_out, b_out, out, mbx);
}